// Round 1
// baseline (326.625 us; speedup 1.0000x reference)
//
#include <hip/hip_runtime.h>
#include <hip/hip_bf16.h>

// ---------------------------------------------------------------------------
// MVoT token processor: out = hidden + MLP_{type}(LN(hidden)), type in {0,1}
// Strategy: partition tokens by type -> one dense bf16 MFMA GEMM pipeline per
// group (half the FLOPs of the masked-dual-MLP reference).
// ---------------------------------------------------------------------------

#define H_DIM 2048

typedef __attribute__((ext_vector_type(8))) short s16x8;   // 8 bf16 (4 VGPRs)
typedef __attribute__((ext_vector_type(4))) float f32x4;   // MFMA accumulator

typedef __attribute__((address_space(1))) const unsigned int gu32;
typedef __attribute__((address_space(3))) unsigned int lu32;

__device__ __forceinline__ void load_lds16(const void* g, void* l) {
  // async global->LDS, 16B per lane; LDS dest = wave-uniform base + lane*16
  __builtin_amdgcn_global_load_lds((gu32*)g, (lu32*)l, 16, 0, 0);
}

// ---------------------------------------------------------------------------
// Partition: stable scan of token_type_ids. text (type==0) first, padded to
// 128 rows, then image (type==1), padded. Single block, deterministic.
// ctrl: [0]=Mt [1]=Mt_pad [2]=Mi [3]=Mi_pad [4]=total_rows
// ---------------------------------------------------------------------------
__global__ __launch_bounds__(256) void partition_kernel(
    const int* __restrict__ tt, int T, int* __restrict__ ctrl,
    int* __restrict__ pos, int* __restrict__ rowid) {
  __shared__ int psum[256];
  const int tid = threadIdx.x;
  const int npt = T >> 8;          // tokens per thread (8192/256 = 32)
  const int base = tid * npt;
  int cnt = 0;
  for (int i = 0; i < npt; ++i) cnt += (tt[base + i] == 0);
  psum[tid] = cnt;
  __syncthreads();
  for (int off = 1; off < 256; off <<= 1) {   // inclusive Hillis-Steele scan
    int v = psum[tid];
    int add = (tid >= off) ? psum[tid - off] : 0;
    __syncthreads();
    psum[tid] = v + add;
    __syncthreads();
  }
  const int Mt = psum[255];
  const int Mt_pad = (Mt + 127) & ~127;
  int tpos = psum[tid] - cnt;      // text tokens before my chunk
  int ipos = base - tpos;          // image tokens before my chunk
  for (int i = 0; i < npt; ++i) {
    const int tok = base + i;
    int p;
    if (tt[tok] == 0) p = tpos++;
    else              p = Mt_pad + ipos++;
    pos[tok] = p;
    rowid[p] = tok;
  }
  const int Mi = T - Mt;
  const int Mi_pad = (Mi + 127) & ~127;
  for (int g = Mt + tid; g < Mt_pad; g += 256) rowid[g] = -1;
  for (int g = Mt_pad + Mi + tid; g < Mt_pad + Mi_pad; g += 256) rowid[g] = -1;
  if (tid == 0) {
    ctrl[0] = Mt; ctrl[1] = Mt_pad; ctrl[2] = Mi; ctrl[3] = Mi_pad;
    ctrl[4] = Mt_pad + Mi_pad;
  }
}

// ---------------------------------------------------------------------------
// Weight transpose + fp32->bf16: W[k][n] -> WT[n][k] (B^T layout for GEMM)
// ---------------------------------------------------------------------------
__global__ __launch_bounds__(256) void transpose_to_bf16(
    const float* __restrict__ W, __hip_bfloat16* __restrict__ WT) {
  __shared__ float tile[32][33];
  const int bx = blockIdx.x, by = blockIdx.y;
  const int tid = threadIdx.x;
  const int r = tid >> 3, c4 = (tid & 7) * 4;
  const float4 v = *(const float4*)(W + (size_t)(by * 32 + r) * H_DIM + bx * 32 + c4);
  tile[r][c4 + 0] = v.x; tile[r][c4 + 1] = v.y;
  tile[r][c4 + 2] = v.z; tile[r][c4 + 3] = v.w;
  __syncthreads();
  union { ushort u[4]; ushort4 v4; } pk;
#pragma unroll
  for (int j = 0; j < 4; ++j) {
    __hip_bfloat16 h = __float2bfloat16(tile[c4 + j][r]);
    pk.u[j] = *(const ushort*)&h;
  }
  *(ushort4*)(WT + (size_t)(bx * 32 + r) * H_DIM + by * 32 + c4) = pk.v4;
}

// ---------------------------------------------------------------------------
// LayerNorm (fp32) -> bf16, scatter row to its gathered position.
// One block (256 thr) per token; 8 elements/thread.
// ---------------------------------------------------------------------------
__global__ __launch_bounds__(256) void ln_scatter_kernel(
    const float* __restrict__ X, const float* __restrict__ gamma,
    const float* __restrict__ beta, const int* __restrict__ pos,
    __hip_bfloat16* __restrict__ XG) {
  const int t = blockIdx.x, tid = threadIdx.x;
  const float* row = X + (size_t)t * H_DIM;
  float x[8];
  {
    float4 v0 = *(const float4*)(row + tid * 8);
    float4 v1 = *(const float4*)(row + tid * 8 + 4);
    x[0] = v0.x; x[1] = v0.y; x[2] = v0.z; x[3] = v0.w;
    x[4] = v1.x; x[5] = v1.y; x[6] = v1.z; x[7] = v1.w;
  }
  float s = 0.f, q = 0.f;
#pragma unroll
  for (int j = 0; j < 8; ++j) { s += x[j]; q += x[j] * x[j]; }
#pragma unroll
  for (int off = 32; off > 0; off >>= 1) {
    s += __shfl_down(s, off);
    q += __shfl_down(q, off);
  }
  __shared__ float ls[4], lq[4];
  if ((tid & 63) == 0) { ls[tid >> 6] = s; lq[tid >> 6] = q; }
  __syncthreads();
  const float S = ls[0] + ls[1] + ls[2] + ls[3];
  const float Q = lq[0] + lq[1] + lq[2] + lq[3];
  const float mu = S * (1.0f / H_DIM);
  const float var = Q * (1.0f / H_DIM) - mu * mu;
  const float rstd = rsqrtf(var + 1e-12f);
  const int p = pos[t];
  float4 g0 = *(const float4*)(gamma + tid * 8);
  float4 g1 = *(const float4*)(gamma + tid * 8 + 4);
  float4 b0 = *(const float4*)(beta + tid * 8);
  float4 b1 = *(const float4*)(beta + tid * 8 + 4);
  float g[8] = {g0.x, g0.y, g0.z, g0.w, g1.x, g1.y, g1.z, g1.w};
  float b[8] = {b0.x, b0.y, b0.z, b0.w, b1.x, b1.y, b1.z, b1.w};
  union { ushort u[8]; int4 v; } pk;
#pragma unroll
  for (int j = 0; j < 8; ++j) {
    float y = (x[j] - mu) * rstd * g[j] + b[j];
    __hip_bfloat16 h = __float2bfloat16(y);
    pk.u[j] = *(const ushort*)&h;
  }
  *(int4*)(XG + (size_t)p * H_DIM + tid * 8) = pk.v;
}

// ---------------------------------------------------------------------------
// 128x128-tile bf16 MFMA GEMM (m97 structure): 256 thr = 4 waves (2x2), each
// wave a 64x64 subtile = 4x4 frags of 16x16x32. A[rows][K], B^T[N][K] both
// staged via global_load_lds(16B). Weight/bias chosen per M-tile by group.
// EPI 0: h = bf16(GELU_exact(acc + b1))      -> Hout
// EPI 1: out[rowid] = resid[rowid] + acc + b2 -> Out (skip rowid<0 pads)
// ---------------------------------------------------------------------------
template <int EPI>
__global__ __launch_bounds__(256, 3) void gemm_kernel(
    const __hip_bfloat16* __restrict__ A,
    const __hip_bfloat16* __restrict__ WTt, const __hip_bfloat16* __restrict__ WTi,
    const float* __restrict__ bt, const float* __restrict__ bi,
    const int* __restrict__ ctrl, const int* __restrict__ rowid,
    __hip_bfloat16* __restrict__ Hout,
    const float* __restrict__ resid, float* __restrict__ Out) {
  const int K = H_DIM;
  const int Mt_pad = ctrl[1];
  const int total = ctrl[4];
  const int m0 = blockIdx.y * 128;
  if (m0 >= total) return;
  const int n0 = blockIdx.x * 128;
  const bool is_text = (m0 < Mt_pad);
  const __hip_bfloat16* WT = is_text ? WTt : WTi;
  const float* bias = is_text ? bt : bi;

  __shared__ __align__(16) __hip_bfloat16 Alds[128 * 32];
  __shared__ __align__(16) __hip_bfloat16 Blds[128 * 32];

  const int tid = threadIdx.x;
  const int wave = tid >> 6, lane = tid & 63;
  const int wm = wave >> 1, wn = wave & 1;

  f32x4 acc[4][4];
  const f32x4 zero = {0.f, 0.f, 0.f, 0.f};
#pragma unroll
  for (int i = 0; i < 4; ++i)
#pragma unroll
    for (int j = 0; j < 4; ++j) acc[i][j] = zero;

  // staging: thread covers row = wave*16 + lane/4 (+64 for 2nd call), 8 bf16
  const int srow = wave * 16 + (lane >> 2);
  const int scol = (lane & 3) * 8;
  const __hip_bfloat16* Ap = A + (size_t)(m0 + srow) * K + scol;
  const __hip_bfloat16* Bp = WT + (size_t)(n0 + srow) * K + scol;
  __hip_bfloat16* AldsB = Alds + wave * 512;  // wave-uniform dest (bytes: *2)
  __hip_bfloat16* BldsB = Blds + wave * 512;

  const int r16 = lane & 15;
  const int kc = (lane >> 4) * 8;  // k-chunk of 8 bf16
  const __hip_bfloat16* Ard = Alds + (wm * 64 + r16) * 32 + kc;
  const __hip_bfloat16* Brd = Blds + (wn * 64 + r16) * 32 + kc;

  for (int kk = 0; kk < K; kk += 32) {
    __syncthreads();  // previous compute's ds_reads done before overwrite
    load_lds16(Ap + kk, AldsB);
    load_lds16(Ap + (size_t)64 * K + kk, AldsB + 2048);
    load_lds16(Bp + kk, BldsB);
    load_lds16(Bp + (size_t)64 * K + kk, BldsB + 2048);
    __syncthreads();  // implies s_waitcnt vmcnt(0): staged data visible
    s16x8 a[4], b[4];
#pragma unroll
    for (int f = 0; f < 4; ++f) {
      a[f] = *(const s16x8*)(Ard + f * 16 * 32);
      b[f] = *(const s16x8*)(Brd + f * 16 * 32);
    }
#pragma unroll
    for (int i = 0; i < 4; ++i)
#pragma unroll
      for (int j = 0; j < 4; ++j)
        acc[i][j] = __builtin_amdgcn_mfma_f32_16x16x32_bf16(a[i], b[j], acc[i][j], 0, 0, 0);
  }

  // epilogue: C/D layout col=lane&15, row=(lane>>4)*4+i  [m89-verified]
  const int r4base = (lane >> 4) * 4;
  if (EPI == 0) {
#pragma unroll
    for (int fm = 0; fm < 4; ++fm) {
      const int grow = m0 + wm * 64 + fm * 16 + r4base;
#pragma unroll
      for (int fn = 0; fn < 4; ++fn) {
        const int gcol = n0 + wn * 64 + fn * 16 + r16;
        const float bb = bias[gcol];
        f32x4 v = acc[fm][fn];
#pragma unroll
        for (int i = 0; i < 4; ++i) {
          float z = v[i] + bb;
          float ge = 0.5f * z * (1.0f + erff(z * 0.70710678118654752f));
          Hout[(size_t)(grow + i) * K + gcol] = __float2bfloat16(ge);
        }
      }
    }
  } else {
#pragma unroll
    for (int fm = 0; fm < 4; ++fm) {
      const int grow = m0 + wm * 64 + fm * 16 + r4base;
      int rid[4];
#pragma unroll
      for (int i = 0; i < 4; ++i) rid[i] = rowid[grow + i];
#pragma unroll
      for (int fn = 0; fn < 4; ++fn) {
        const int gcol = n0 + wn * 64 + fn * 16 + r16;
        const float bb = bias[gcol];
        f32x4 v = acc[fm][fn];
#pragma unroll
        for (int i = 0; i < 4; ++i) {
          if (rid[i] >= 0) {
            const size_t o = (size_t)rid[i] * K + gcol;
            Out[o] = resid[o] + v[i] + bb;
          }
        }
      }
    }
  }
}

// ---------------------------------------------------------------------------
extern "C" void kernel_launch(void* const* d_in, const int* in_sizes, int n_in,
                              void* d_out, int out_size, void* d_ws, size_t ws_size,
                              hipStream_t stream) {
  const float* hidden = (const float*)d_in[0];
  const int*   tt     = (const int*)d_in[1];
  const float* gamma  = (const float*)d_in[2];
  const float* beta   = (const float*)d_in[3];
  const float* tw1    = (const float*)d_in[4];
  const float* tb1    = (const float*)d_in[5];
  const float* tw2    = (const float*)d_in[6];
  const float* tb2    = (const float*)d_in[7];
  const float* iw1    = (const float*)d_in[8];
  const float* ib1    = (const float*)d_in[9];
  const float* iw2    = (const float*)d_in[10];
  const float* ib2    = (const float*)d_in[11];
  float* out = (float*)d_out;

  const int T = in_sizes[1];          // 8192 tokens
  const int K = H_DIM;
  const int maxtiles = T / 128 + 2;   // both groups padded to 128 rows
  const int maxrows = maxtiles * 128;

  char* ws = (char*)d_ws;
  int* ctrl  = (int*)(ws);
  int* pos   = (int*)(ws + 4096);
  int* rowid = (int*)(ws + 65536);
  const size_t WOFF = 131072;
  const size_t WSZ = (size_t)K * K * sizeof(__hip_bfloat16);
  __hip_bfloat16* tw1T = (__hip_bfloat16*)(ws + WOFF);
  __hip_bfloat16* tw2T = (__hip_bfloat16*)(ws + WOFF + WSZ);
  __hip_bfloat16* iw1T = (__hip_bfloat16*)(ws + WOFF + 2 * WSZ);
  __hip_bfloat16* iw2T = (__hip_bfloat16*)(ws + WOFF + 3 * WSZ);
  __hip_bfloat16* xg   = (__hip_bfloat16*)(ws + WOFF + 4 * WSZ);
  __hip_bfloat16* hb   = xg + (size_t)maxrows * K;

  // zero gathered-xn so pad rows are 0 (pad h/out rows are discarded anyway)
  hipMemsetAsync(xg, 0, (size_t)maxrows * K * sizeof(__hip_bfloat16), stream);

  partition_kernel<<<1, 256, 0, stream>>>(tt, T, ctrl, pos, rowid);

  dim3 tg(K / 32, K / 32);
  transpose_to_bf16<<<tg, 256, 0, stream>>>(tw1, tw1T);
  transpose_to_bf16<<<tg, 256, 0, stream>>>(tw2, tw2T);
  transpose_to_bf16<<<tg, 256, 0, stream>>>(iw1, iw1T);
  transpose_to_bf16<<<tg, 256, 0, stream>>>(iw2, iw2T);

  ln_scatter_kernel<<<T, 256, 0, stream>>>(hidden, gamma, beta, pos, xg);

  dim3 gg(K / 128, maxtiles);
  gemm_kernel<0><<<gg, 256, 0, stream>>>(xg, tw1T, iw1T, tb1, ib1, ctrl, rowid,
                                         hb, nullptr, nullptr);
  gemm_kernel<1><<<gg, 256, 0, stream>>>(hb, tw2T, iw2T, tb2, ib2, ctrl, rowid,
                                         nullptr, hidden, out);
}